// Round 7
// baseline (451.720 us; speedup 1.0000x reference)
//
#include <hip/hip_runtime.h>
#include <hip/hip_bf16.h>

// GIN classifier. R6: gemm1 rebuilt as wave-tile direct-from-global MFMA
// (no LDS/barriers in K-loop; B is 96KB L2-resident; A read at full-line
// granularity; 12500 independent waves). Rest unchanged from R5.

#define N_NODES 100000
#define N_EDGES 800000
#define N_GRAPHS 128
#define NB_SCAN 391   // ceil(N_NODES/256)
#define LDP 136       // bf16 LDS row stride (mlp): 2-way bank alias only (free)
#define FLDP 68       // f32 row stride for pool staging

typedef __bf16 bf16x8 __attribute__((ext_vector_type(8)));
typedef float f32x4 __attribute__((ext_vector_type(4)));
typedef unsigned short ushort_t;
typedef unsigned int uint_t;

static __device__ __forceinline__ ushort_t f2b(float f) {
    uint_t u = __builtin_bit_cast(uint_t, f);
    uint_t r = (u + 0x7fffu + ((u >> 16) & 1u)) >> 16;   // RNE
    return (ushort_t)r;
}
static __device__ __forceinline__ float b2f(ushort_t u) {
    return __builtin_bit_cast(float, (uint_t)u << 16);
}

// ------------- all weight transposes in one kernel: Wt[c*K+k] = bf16(W[k*N+c])
__global__ __launch_bounds__(256) void wt_all_k(
        const float* __restrict__ w1a, const float* __restrict__ w1b,
        const float* __restrict__ w2a, const float* __restrict__ w2b,
        const float* __restrict__ w3a, const float* __restrict__ w3b,
        ushort_t* __restrict__ o1a, ushort_t* __restrict__ o1b,
        ushort_t* __restrict__ o2a, ushort_t* __restrict__ o2b,
        ushort_t* __restrict__ o3a, ushort_t* __restrict__ o3b) {
    int t = blockIdx.x * 256 + threadIdx.x;
    const float* W; ushort_t* O; int K, N, i;
    if      (t <  49152) { W = w1a; O = o1a; K = 384; N = 128; i = t; }
    else if (t <  65536) { W = w1b; O = o1b; K = 128; N = 128; i = t - 49152; }
    else if (t <  81920) { W = w2a; O = o2a; K = 128; N = 128; i = t - 65536; }
    else if (t <  98304) { W = w2b; O = o2b; K = 128; N = 128; i = t - 81920; }
    else if (t < 114688) { W = w3a; O = o3a; K = 128; N = 128; i = t - 98304; }
    else if (t < 122880) { W = w3b; O = o3b; K = 128; N = 64;  i = t - 114688; }
    else return;
    int k = i / N, c = i % N;
    O[c * K + k] = f2b(W[i]);
}

// ---------------- D1: C[M,128] = bf16(A fp32 [M,384]) @ Wt ------------------
// Wave-tile 16x64, A direct from global (16 full cache lines per k-step),
// B from L2-hot Wt, fp32->bf16 via HW cvt. No barriers in K-loop.
// 100000 rows = 6250 row-groups x 2 col-halves = 12500 waves exactly.
__global__ __launch_bounds__(256) void gemm1_k(const float* __restrict__ A,
                                               const ushort_t* __restrict__ Wt,
                                               ushort_t* __restrict__ C) {
    constexpr int K = 384;
    constexpr int EP = 72;                   // epilogue LDS row stride (bf16)
    __shared__ ushort_t El[4 * 16 * EP];     // 9.2 KB, per-wave regions

    const int tid  = threadIdx.x;
    const int lane = tid & 63;
    const int wid  = tid >> 6;
    const int wv   = blockIdx.x * 4 + wid;   // 0..12499
    const int row0 = (wv >> 1) * 16;
    const int colh = wv & 1;                 // 0: cols 0-63, 1: cols 64-127
    const int l15  = lane & 15;
    const int kg   = lane >> 4;

    const float*    pA = A  + (size_t)(row0 + l15) * K + kg * 8;
    const ushort_t* pB = Wt + (size_t)(colh * 64 + l15) * K + kg * 8;

    f32x4 acc[4];
    #pragma unroll
    for (int j = 0; j < 4; ++j) acc[j] = f32x4{0.f, 0.f, 0.f, 0.f};

    #pragma unroll
    for (int kk = 0; kk < 12; ++kk) {
        float4 va = *reinterpret_cast<const float4*>(pA + kk * 32);
        float4 vb = *reinterpret_cast<const float4*>(pA + kk * 32 + 4);
        bf16x8 af;
        af[0] = (__bf16)va.x; af[1] = (__bf16)va.y;
        af[2] = (__bf16)va.z; af[3] = (__bf16)va.w;
        af[4] = (__bf16)vb.x; af[5] = (__bf16)vb.y;
        af[6] = (__bf16)vb.z; af[7] = (__bf16)vb.w;
        #pragma unroll
        for (int j = 0; j < 4; ++j) {
            bf16x8 bf = *reinterpret_cast<const bf16x8*>(pB + (size_t)j * 16 * K + kk * 32);
            acc[j] = __builtin_amdgcn_mfma_f32_16x16x32_bf16(af, bf, acc[j], 0, 0, 0);
        }
    }

    // epilogue: stage wave tile in LDS, full-128B-line coalesced stores
    ushort_t* Ew = &El[wid * 16 * EP];
    #pragma unroll
    for (int j = 0; j < 4; ++j)
        #pragma unroll
        for (int q = 0; q < 4; ++q)
            Ew[(kg * 4 + q) * EP + j * 16 + l15] = f2b(acc[j][q]);
    __syncthreads();
    #pragma unroll
    for (int p = 0; p < 2; ++p) {
        int idx = p * 64 + lane;
        int r = idx >> 3, c8 = idx & 7;
        *reinterpret_cast<uint4*>(C + (size_t)(row0 + r) * 128 + colh * 64 + c8 * 8) =
            *reinterpret_cast<const uint4*>(&Ew[r * EP + c8 * 8]);
    }
}

// ---------------- CSR build ----------------
__global__ __launch_bounds__(256) void hist_k(const int* __restrict__ dst,
                                              int* __restrict__ deg) {
    int e = blockIdx.x * 256 + threadIdx.x;
    if (e < N_EDGES) atomicAdd(&deg[dst[e]], 1);
}

__global__ __launch_bounds__(256) void scan1_k(const int* __restrict__ deg,
                                               int* __restrict__ tmp,
                                               int* __restrict__ bsum) {
    __shared__ int s[256];
    int i = blockIdx.x * 256 + threadIdx.x;
    int t = threadIdx.x;
    s[t] = (i < N_NODES) ? deg[i] : 0;
    __syncthreads();
    for (int off = 1; off < 256; off <<= 1) {
        int v = (t >= off) ? s[t - off] : 0;
        __syncthreads();
        s[t] += v;
        __syncthreads();
    }
    if (i < N_NODES) tmp[i] = s[t];
    if (t == 255) bsum[blockIdx.x] = s[255];
}

__global__ __launch_bounds__(512) void scan2_k(int* __restrict__ bsum) {
    __shared__ int s[512];
    int t = threadIdx.x;
    s[t] = (t < NB_SCAN) ? bsum[t] : 0;
    __syncthreads();
    for (int off = 1; off < 512; off <<= 1) {
        int v = (t >= off) ? s[t - off] : 0;
        __syncthreads();
        s[t] += v;
        __syncthreads();
    }
    if (t < NB_SCAN) bsum[t] = s[t];
}

__global__ __launch_bounds__(256) void scan3_k(const int* __restrict__ tmp,
                                               const int* __restrict__ deg,
                                               const int* __restrict__ bsum,
                                               int* __restrict__ row_start) {
    int i = blockIdx.x * 256 + threadIdx.x;
    if (i >= N_NODES) return;
    int boff = (blockIdx.x > 0) ? bsum[blockIdx.x - 1] : 0;
    row_start[i] = tmp[i] - deg[i] + boff;
}

__global__ __launch_bounds__(256) void fill_k(const int* __restrict__ src,
                                              const int* __restrict__ dst,
                                              int* __restrict__ row_start,
                                              int* __restrict__ csr_src) {
    int e = blockIdx.x * 256 + threadIdx.x;
    if (e >= N_EDGES) return;
    int idx = atomicAdd(&row_start[dst[e]], 1);
    csr_src[idx] = src[e];
}

// ---------- gather + BN + ReLU, one wave per node, 4 neighbor slots ----------
__global__ __launch_bounds__(256) void gather_bn_k(
        const ushort_t* __restrict__ Yin,
        const int* __restrict__ csr, const int* __restrict__ rend,
        const int* __restrict__ deg,
        const float* __restrict__ epsp, const float* __restrict__ ba,
        const float* __restrict__ g, const float* __restrict__ be,
        const float* __restrict__ mm, const float* __restrict__ vv,
        ushort_t* __restrict__ H, int nwaves) {
    const int gwid = (blockIdx.x * 256 + threadIdx.x) >> 6;
    const int lane = threadIdx.x & 63;
    const int l15  = lane & 15;
    const int slot = lane >> 4;
    const int c0   = l15 * 8;

    float ep = 1.0f + epsp[0];
    float sc[8], sh[8];
    #pragma unroll
    for (int jj = 0; jj < 8; ++jj) {
        int c = c0 + jj;
        float s = g[c] * rsqrtf(vv[c] + 1e-5f);
        sc[jj] = s;
        sh[jj] = (ba[c] - mm[c]) * s + be[c];
    }

    for (int node = gwid; node < N_NODES; node += nwaves) {
        int end = rend[node];
        int d = deg[node];
        int st = end - d;
        uint4 ow = *reinterpret_cast<const uint4*>(Yin + (size_t)node * 128 + c0);
        int nlim = (d > 64) ? 64 : d;
        int nb = (lane < nlim) ? csr[st + lane] : 0;

        float acc[8] = {0.f, 0.f, 0.f, 0.f, 0.f, 0.f, 0.f, 0.f};
        for (int j0 = 0; j0 < nlim; j0 += 8) {
            int jA = j0 + slot;
            int jB = j0 + 4 + slot;
            int ia = __shfl(nb, jA & 63);
            int ib = __shfl(nb, jB & 63);
            uint4 wa = *reinterpret_cast<const uint4*>(Yin + (size_t)ia * 128 + c0);
            uint4 wb = *reinterpret_cast<const uint4*>(Yin + (size_t)ib * 128 + c0);
            float fa = (jA < nlim) ? 1.f : 0.f;
            float fb = (jB < nlim) ? 1.f : 0.f;
            uint_t ua[4] = {wa.x, wa.y, wa.z, wa.w};
            uint_t ub[4] = {wb.x, wb.y, wb.z, wb.w};
            #pragma unroll
            for (int p = 0; p < 4; ++p) {
                acc[2 * p]     += fa * b2f((ushort_t)(ua[p] & 0xffff));
                acc[2 * p + 1] += fa * b2f((ushort_t)(ua[p] >> 16));
                acc[2 * p]     += fb * b2f((ushort_t)(ub[p] & 0xffff));
                acc[2 * p + 1] += fb * b2f((ushort_t)(ub[p] >> 16));
            }
        }
        for (int j = st + 64; j < end; ++j) {
            if (slot == 0) {
                int idx = csr[j];
                uint4 w = *reinterpret_cast<const uint4*>(Yin + (size_t)idx * 128 + c0);
                uint_t uw[4] = {w.x, w.y, w.z, w.w};
                #pragma unroll
                for (int p = 0; p < 4; ++p) {
                    acc[2 * p]     += b2f((ushort_t)(uw[p] & 0xffff));
                    acc[2 * p + 1] += b2f((ushort_t)(uw[p] >> 16));
                }
            }
        }
        #pragma unroll
        for (int jj = 0; jj < 8; ++jj) {
            acc[jj] += __shfl_xor(acc[jj], 16);
            acc[jj] += __shfl_xor(acc[jj], 32);
        }
        uint_t uo[4] = {ow.x, ow.y, ow.z, ow.w};
        ushort_t rr[8];
        #pragma unroll
        for (int p = 0; p < 4; ++p) {
            float o0 = b2f((ushort_t)(uo[p] & 0xffff));
            float o1 = b2f((ushort_t)(uo[p] >> 16));
            float t0 = sc[2 * p] * (ep * o0 + acc[2 * p]) + sh[2 * p];
            float t1 = sc[2 * p + 1] * (ep * o1 + acc[2 * p + 1]) + sh[2 * p + 1];
            rr[2 * p]     = f2b(fmaxf(t0, 0.f));
            rr[2 * p + 1] = f2b(fmaxf(t1, 0.f));
        }
        if (slot == 0) {
            uint4 packed;
            packed.x = (uint_t)rr[0] | ((uint_t)rr[1] << 16);
            packed.y = (uint_t)rr[2] | ((uint_t)rr[3] << 16);
            packed.z = (uint_t)rr[4] | ((uint_t)rr[5] << 16);
            packed.w = (uint_t)rr[6] | ((uint_t)rr[7] << 16);
            *reinterpret_cast<uint4*>(H + (size_t)node * 128 + c0) = packed;
        }
    }
}

// -------- MLP pair: X=relu(H@Wb+bias); TAIL? pool(X) : Yout = X@Wa2 ----------
template<bool TAIL>
__global__ __launch_bounds__(256) void mlp_k(const ushort_t* __restrict__ Hin,
                                             const ushort_t* __restrict__ Wb,
                                             const float* __restrict__ bias1,
                                             const ushort_t* __restrict__ Wa2,
                                             ushort_t* __restrict__ Yout,
                                             const int* __restrict__ batch,
                                             float* __restrict__ pooled, int M) {
    constexpr int BM = 64;
    constexpr int NJ1 = TAIL ? 2 : 4;       // N1 = 64 or 128
    __shared__ ushort_t Hl[BM * LDP];
    __shared__ ushort_t Xl[BM * LDP];       // also f32 pool staging [64][FLDP]
    float* Fl = (float*)Xl;

    const int tid  = threadIdx.x;
    const int lane = tid & 63;
    const int wid  = tid >> 6;
    const int wrow = wid >> 1;
    const int wcol = wid & 1;
    const int l15  = lane & 15;
    const int kg   = lane >> 4;
    const int row0 = blockIdx.x * BM;

    #pragma unroll
    for (int p = 0; p < 4; ++p) {
        int idx = tid + p * 256;
        int r = idx >> 4, c16 = idx & 15;
        int gr = row0 + r;
        if (gr > M - 1) gr = M - 1;
        *reinterpret_cast<uint4*>(&Hl[r * LDP + c16 * 8]) =
            *reinterpret_cast<const uint4*>(Hin + (size_t)gr * 128 + c16 * 8);
    }
    __syncthreads();

    f32x4 acc1[2][NJ1];
    #pragma unroll
    for (int i = 0; i < 2; ++i)
        #pragma unroll
        for (int j = 0; j < NJ1; ++j)
            acc1[i][j] = f32x4{0.f, 0.f, 0.f, 0.f};
    #pragma unroll
    for (int kk = 0; kk < 4; ++kk) {
        bf16x8 a0 = *reinterpret_cast<const bf16x8*>(&Hl[(wrow * 32 + l15) * LDP + kk * 32 + kg * 8]);
        bf16x8 a1 = *reinterpret_cast<const bf16x8*>(&Hl[(wrow * 32 + 16 + l15) * LDP + kk * 32 + kg * 8]);
        #pragma unroll
        for (int j = 0; j < NJ1; ++j) {
            int col = wcol * (16 * NJ1) + j * 16 + l15;
            bf16x8 b = *reinterpret_cast<const bf16x8*>(Wb + (size_t)col * 128 + kk * 32 + kg * 8);
            acc1[0][j] = __builtin_amdgcn_mfma_f32_16x16x32_bf16(a0, b, acc1[0][j], 0, 0, 0);
            acc1[1][j] = __builtin_amdgcn_mfma_f32_16x16x32_bf16(a1, b, acc1[1][j], 0, 0, 0);
        }
    }

    if constexpr (TAIL) {
        #pragma unroll
        for (int i = 0; i < 2; ++i)
            #pragma unroll
            for (int j = 0; j < NJ1; ++j) {
                int col = wcol * 32 + j * 16 + l15;
                float bi = bias1[col];
                #pragma unroll
                for (int q = 0; q < 4; ++q) {
                    int row = wrow * 32 + i * 16 + kg * 4 + q;
                    Fl[row * FLDP + col] = fmaxf(acc1[i][j][q] + bi, 0.f);
                }
            }
        __syncthreads();
        int col = tid & 63;
        int qq  = tid >> 6;
        float a = 0.f;
        int cur = -1;
        for (int rr = 0; rr < 16; ++rr) {
            int r = qq * 16 + rr;
            int gr = row0 + r;
            if (gr >= M) break;
            int b = batch[gr];
            if (b != cur) {
                if (cur >= 0) atomicAdd(&pooled[cur * 64 + col], a);
                a = 0.f;
                cur = b;
            }
            a += Fl[r * FLDP + col];
        }
        if (cur >= 0) atomicAdd(&pooled[cur * 64 + col], a);
    } else {
        #pragma unroll
        for (int i = 0; i < 2; ++i)
            #pragma unroll
            for (int j = 0; j < NJ1; ++j) {
                int col = wcol * 64 + j * 16 + l15;
                float bi = bias1[col];
                #pragma unroll
                for (int q = 0; q < 4; ++q) {
                    int row = wrow * 32 + i * 16 + kg * 4 + q;
                    Xl[row * LDP + col] = f2b(fmaxf(acc1[i][j][q] + bi, 0.f));
                }
            }
        __syncthreads();

        f32x4 acc2[2][4];
        #pragma unroll
        for (int i = 0; i < 2; ++i)
            #pragma unroll
            for (int j = 0; j < 4; ++j)
                acc2[i][j] = f32x4{0.f, 0.f, 0.f, 0.f};
        #pragma unroll
        for (int kk = 0; kk < 4; ++kk) {
            bf16x8 a0 = *reinterpret_cast<const bf16x8*>(&Xl[(wrow * 32 + l15) * LDP + kk * 32 + kg * 8]);
            bf16x8 a1 = *reinterpret_cast<const bf16x8*>(&Xl[(wrow * 32 + 16 + l15) * LDP + kk * 32 + kg * 8]);
            #pragma unroll
            for (int j = 0; j < 4; ++j) {
                int col = wcol * 64 + j * 16 + l15;
                bf16x8 b = *reinterpret_cast<const bf16x8*>(Wa2 + (size_t)col * 128 + kk * 32 + kg * 8);
                acc2[0][j] = __builtin_amdgcn_mfma_f32_16x16x32_bf16(a0, b, acc2[0][j], 0, 0, 0);
                acc2[1][j] = __builtin_amdgcn_mfma_f32_16x16x32_bf16(a1, b, acc2[1][j], 0, 0, 0);
            }
        }
        #pragma unroll
        for (int i = 0; i < 2; ++i)
            #pragma unroll
            for (int j = 0; j < 4; ++j) {
                int col = wcol * 64 + j * 16 + l15;
                #pragma unroll
                for (int q = 0; q < 4; ++q) {
                    int row = wrow * 32 + i * 16 + kg * 4 + q;
                    Hl[row * LDP + col] = f2b(acc2[i][j][q]);
                }
            }
        __syncthreads();
        #pragma unroll
        for (int p = 0; p < 4; ++p) {
            int idx = tid + p * 256;
            int r = idx >> 4, c16 = idx & 15;
            int gr = row0 + r;
            if (gr < M)
                *reinterpret_cast<uint4*>(Yout + (size_t)gr * 128 + c16 * 8) =
                    *reinterpret_cast<const uint4*>(&Hl[r * LDP + c16 * 8]);
        }
    }
}

// ---------------- classifier ----------------
__global__ __launch_bounds__(256) void classifier_k(const float* __restrict__ pooled,
                                                    const float* __restrict__ wc,
                                                    const float* __restrict__ bc,
                                                    float* __restrict__ out) {
    int t = threadIdx.x;
    int gidx = t >> 1, c = t & 1;
    float s = bc[c];
    #pragma unroll
    for (int k = 0; k < 64; ++k)
        s += pooled[gidx * 64 + k] * wc[k * 2 + c];
    out[gidx * 2 + c] = s;
}

extern "C" void kernel_launch(void* const* d_in, const int* in_sizes, int n_in,
                              void* d_out, int out_size, void* d_ws, size_t ws_size,
                              hipStream_t stream) {
    const float* x     = (const float*)d_in[0];
    const int*   ei    = (const int*)d_in[1];
    const int*   src   = ei;
    const int*   dst   = ei + N_EDGES;
    const int*   batch = (const int*)d_in[2];
    const float* eps1 = (const float*)d_in[3];
    const float* w1a  = (const float*)d_in[4];
    const float* b1a  = (const float*)d_in[5];
    const float* g1   = (const float*)d_in[6];
    const float* be1  = (const float*)d_in[7];
    const float* m1   = (const float*)d_in[8];
    const float* v1   = (const float*)d_in[9];
    const float* w1b  = (const float*)d_in[10];
    const float* b1b  = (const float*)d_in[11];
    const float* eps2 = (const float*)d_in[12];
    const float* w2a  = (const float*)d_in[13];
    const float* b2a  = (const float*)d_in[14];
    const float* g2   = (const float*)d_in[15];
    const float* be2  = (const float*)d_in[16];
    const float* m2   = (const float*)d_in[17];
    const float* v2   = (const float*)d_in[18];
    const float* w2b  = (const float*)d_in[19];
    const float* b2b  = (const float*)d_in[20];
    const float* eps3 = (const float*)d_in[21];
    const float* w3a  = (const float*)d_in[22];
    const float* b3a  = (const float*)d_in[23];
    const float* g3   = (const float*)d_in[24];
    const float* be3  = (const float*)d_in[25];
    const float* m3   = (const float*)d_in[26];
    const float* v3   = (const float*)d_in[27];
    const float* w3b  = (const float*)d_in[28];
    const float* b3b  = (const float*)d_in[29];
    const float* wc   = (const float*)d_in[30];
    const float* bc   = (const float*)d_in[31];
    float* out = (float*)d_out;

    // workspace layout
    ushort_t* Y = (ushort_t*)d_ws;             // [100000,128] bf16
    ushort_t* H = Y + 12800000;                // [100000,128] bf16
    ushort_t* wt1a = H + 12800000;             // 384*128
    ushort_t* wt1b = wt1a + 49152;             // 128*128
    ushort_t* wt2a = wt1b + 16384;
    ushort_t* wt2b = wt2a + 16384;
    ushort_t* wt3a = wt2b + 16384;
    ushort_t* wt3b = wt3a + 16384;             // 64*128
    float* pooled = (float*)(wt3b + 8192);     // [128,64]
    int* ideg = (int*)(pooled + 8192);         // [100000]
    int* irow = ideg + N_NODES;
    int* itmp = irow + N_NODES;
    int* icsr = itmp + N_NODES;                // [800000]
    int* ibsum = icsr + N_EDGES;               // [391]

    const int M = N_NODES;
    const int gGemm = (M + 63) / 64;           // 1563
    const int gG1   = 3125;                    // 12500 waves = 6250 rowgrp x 2
    const int gEdge = (N_EDGES + 255) / 256;   // 3125
    const int gNode = NB_SCAN;                 // 391
    const int gGath = 2048;                    // 8192 waves
    const int nwaves = gGath * 4;

    // ---- all weight transposes (one dispatch) ----
    wt_all_k<<<480, 256, 0, stream>>>(w1a, w1b, w2a, w2b, w3a, w3b,
                                      wt1a, wt1b, wt2a, wt2b, wt3a, wt3b);

    // ---- build CSR ----
    hipMemsetAsync(ideg, 0, N_NODES * sizeof(int), stream);
    hist_k<<<gEdge, 256, 0, stream>>>(dst, ideg);
    scan1_k<<<gNode, 256, 0, stream>>>(ideg, itmp, ibsum);
    scan2_k<<<1, 512, 0, stream>>>(ibsum);
    scan3_k<<<gNode, 256, 0, stream>>>(itmp, ideg, ibsum, irow);
    fill_k<<<gEdge, 256, 0, stream>>>(src, dst, irow, icsr);
    hipMemsetAsync(pooled, 0, (size_t)N_GRAPHS * 64 * sizeof(float), stream);

    // ---- D1: Y1 = x @ w1a ----
    gemm1_k<<<gG1, 256, 0, stream>>>(x, wt1a, Y);

    // ---- layer 1 ----
    gather_bn_k<<<gGath, 256, 0, stream>>>(Y, icsr, irow, ideg, eps1, b1a, g1, be1, m1, v1, H, nwaves);
    mlp_k<false><<<gGemm, 256, 0, stream>>>(H, wt1b, b1b, wt2a, Y, nullptr, nullptr, M);

    // ---- layer 2 ----
    gather_bn_k<<<gGath, 256, 0, stream>>>(Y, icsr, irow, ideg, eps2, b2a, g2, be2, m2, v2, H, nwaves);
    mlp_k<false><<<gGemm, 256, 0, stream>>>(H, wt2b, b2b, wt3a, Y, nullptr, nullptr, M);

    // ---- layer 3 ----
    gather_bn_k<<<gGath, 256, 0, stream>>>(Y, icsr, irow, ideg, eps3, b3a, g3, be3, m3, v3, H, nwaves);
    mlp_k<true><<<gGemm, 256, 0, stream>>>(H, wt3b, b3b, nullptr, nullptr, batch, pooled, M);

    // ---- classifier ----
    classifier_k<<<1, 256, 0, stream>>>(pooled, wc, bc, out);
}

// Round 8
// 451.311 us; speedup vs baseline: 1.0009x; 1.0009x over previous
//
#include <hip/hip_runtime.h>
#include <hip/hip_bf16.h>

// GIN classifier. R7: gemm1 wave-tile keeps R6 traffic pattern but hoists the
// whole A-fragment into a 24-deep independent register load burst (static
// indices -> registers), so HBM latency is paid once per wave, not 12x.
// Rest unchanged from R6.

#define N_NODES 100000
#define N_EDGES 800000
#define N_GRAPHS 128
#define NB_SCAN 391   // ceil(N_NODES/256)
#define LDP 136       // bf16 LDS row stride (mlp): 2-way bank alias only (free)
#define FLDP 68       // f32 row stride for pool staging

typedef __bf16 bf16x8 __attribute__((ext_vector_type(8)));
typedef float f32x4 __attribute__((ext_vector_type(4)));
typedef unsigned short ushort_t;
typedef unsigned int uint_t;

static __device__ __forceinline__ ushort_t f2b(float f) {
    uint_t u = __builtin_bit_cast(uint_t, f);
    uint_t r = (u + 0x7fffu + ((u >> 16) & 1u)) >> 16;   // RNE
    return (ushort_t)r;
}
static __device__ __forceinline__ float b2f(ushort_t u) {
    return __builtin_bit_cast(float, (uint_t)u << 16);
}

// ------------- all weight transposes in one kernel: Wt[c*K+k] = bf16(W[k*N+c])
__global__ __launch_bounds__(256) void wt_all_k(
        const float* __restrict__ w1a, const float* __restrict__ w1b,
        const float* __restrict__ w2a, const float* __restrict__ w2b,
        const float* __restrict__ w3a, const float* __restrict__ w3b,
        ushort_t* __restrict__ o1a, ushort_t* __restrict__ o1b,
        ushort_t* __restrict__ o2a, ushort_t* __restrict__ o2b,
        ushort_t* __restrict__ o3a, ushort_t* __restrict__ o3b) {
    int t = blockIdx.x * 256 + threadIdx.x;
    const float* W; ushort_t* O; int K, N, i;
    if      (t <  49152) { W = w1a; O = o1a; K = 384; N = 128; i = t; }
    else if (t <  65536) { W = w1b; O = o1b; K = 128; N = 128; i = t - 49152; }
    else if (t <  81920) { W = w2a; O = o2a; K = 128; N = 128; i = t - 65536; }
    else if (t <  98304) { W = w2b; O = o2b; K = 128; N = 128; i = t - 81920; }
    else if (t < 114688) { W = w3a; O = o3a; K = 128; N = 128; i = t - 98304; }
    else if (t < 122880) { W = w3b; O = o3b; K = 128; N = 64;  i = t - 114688; }
    else return;
    int k = i / N, c = i % N;
    O[c * K + k] = f2b(W[i]);
}

// ---------------- D1: C[M,128] = bf16(A fp32 [M,384]) @ Wt ------------------
// Wave-tile 16x64. Entire per-lane A fragment (24 float4, all independent)
// loaded in one burst before any use -> 24 outstanding loads/wave. Then
// convert + MFMA against L2-hot Wt. No barriers until epilogue.
__global__ __launch_bounds__(256) void gemm1_k(const float* __restrict__ A,
                                               const ushort_t* __restrict__ Wt,
                                               ushort_t* __restrict__ C) {
    constexpr int K = 384;
    constexpr int EP = 72;                   // epilogue LDS row stride (bf16)
    __shared__ ushort_t El[4 * 16 * EP];     // 9.2 KB, per-wave regions

    const int tid  = threadIdx.x;
    const int lane = tid & 63;
    const int wid  = tid >> 6;
    const int wv   = blockIdx.x * 4 + wid;   // 0..12499
    const int row0 = (wv >> 1) * 16;
    const int colh = wv & 1;                 // 0: cols 0-63, 1: cols 64-127
    const int l15  = lane & 15;
    const int kg   = lane >> 4;

    const float*    pA = A  + (size_t)(row0 + l15) * K + kg * 8;
    const ushort_t* pB = Wt + (size_t)(colh * 64 + l15) * K + kg * 8;

    // ---- burst: all 24 independent A loads in flight ----
    float4 va[24];
    #pragma unroll
    for (int p = 0; p < 24; ++p)
        va[p] = *reinterpret_cast<const float4*>(pA + (p >> 1) * 32 + (p & 1) * 4);

    f32x4 acc[4];
    #pragma unroll
    for (int j = 0; j < 4; ++j) acc[j] = f32x4{0.f, 0.f, 0.f, 0.f};

    #pragma unroll
    for (int kk = 0; kk < 12; ++kk) {
        float4 x0 = va[2 * kk], x1 = va[2 * kk + 1];
        bf16x8 af;
        af[0] = (__bf16)x0.x; af[1] = (__bf16)x0.y;
        af[2] = (__bf16)x0.z; af[3] = (__bf16)x0.w;
        af[4] = (__bf16)x1.x; af[5] = (__bf16)x1.y;
        af[6] = (__bf16)x1.z; af[7] = (__bf16)x1.w;
        #pragma unroll
        for (int j = 0; j < 4; ++j) {
            bf16x8 bf = *reinterpret_cast<const bf16x8*>(pB + (size_t)j * 16 * K + kk * 32);
            acc[j] = __builtin_amdgcn_mfma_f32_16x16x32_bf16(af, bf, acc[j], 0, 0, 0);
        }
    }

    // epilogue: stage wave tile in LDS, full-128B-line coalesced stores
    ushort_t* Ew = &El[wid * 16 * EP];
    #pragma unroll
    for (int j = 0; j < 4; ++j)
        #pragma unroll
        for (int q = 0; q < 4; ++q)
            Ew[(kg * 4 + q) * EP + j * 16 + l15] = f2b(acc[j][q]);
    __syncthreads();
    #pragma unroll
    for (int p = 0; p < 2; ++p) {
        int idx = p * 64 + lane;
        int r = idx >> 3, c8 = idx & 7;
        *reinterpret_cast<uint4*>(C + (size_t)(row0 + r) * 128 + colh * 64 + c8 * 8) =
            *reinterpret_cast<const uint4*>(&Ew[r * EP + c8 * 8]);
    }
}

// ---------------- CSR build ----------------
__global__ __launch_bounds__(256) void hist_k(const int* __restrict__ dst,
                                              int* __restrict__ deg) {
    int e = blockIdx.x * 256 + threadIdx.x;
    if (e < N_EDGES) atomicAdd(&deg[dst[e]], 1);
}

__global__ __launch_bounds__(256) void scan1_k(const int* __restrict__ deg,
                                               int* __restrict__ tmp,
                                               int* __restrict__ bsum) {
    __shared__ int s[256];
    int i = blockIdx.x * 256 + threadIdx.x;
    int t = threadIdx.x;
    s[t] = (i < N_NODES) ? deg[i] : 0;
    __syncthreads();
    for (int off = 1; off < 256; off <<= 1) {
        int v = (t >= off) ? s[t - off] : 0;
        __syncthreads();
        s[t] += v;
        __syncthreads();
    }
    if (i < N_NODES) tmp[i] = s[t];
    if (t == 255) bsum[blockIdx.x] = s[255];
}

__global__ __launch_bounds__(512) void scan2_k(int* __restrict__ bsum) {
    __shared__ int s[512];
    int t = threadIdx.x;
    s[t] = (t < NB_SCAN) ? bsum[t] : 0;
    __syncthreads();
    for (int off = 1; off < 512; off <<= 1) {
        int v = (t >= off) ? s[t - off] : 0;
        __syncthreads();
        s[t] += v;
        __syncthreads();
    }
    if (t < NB_SCAN) bsum[t] = s[t];
}

__global__ __launch_bounds__(256) void scan3_k(const int* __restrict__ tmp,
                                               const int* __restrict__ deg,
                                               const int* __restrict__ bsum,
                                               int* __restrict__ row_start) {
    int i = blockIdx.x * 256 + threadIdx.x;
    if (i >= N_NODES) return;
    int boff = (blockIdx.x > 0) ? bsum[blockIdx.x - 1] : 0;
    row_start[i] = tmp[i] - deg[i] + boff;
}

__global__ __launch_bounds__(256) void fill_k(const int* __restrict__ src,
                                              const int* __restrict__ dst,
                                              int* __restrict__ row_start,
                                              int* __restrict__ csr_src) {
    int e = blockIdx.x * 256 + threadIdx.x;
    if (e >= N_EDGES) return;
    int idx = atomicAdd(&row_start[dst[e]], 1);
    csr_src[idx] = src[e];
}

// ---------- gather + BN + ReLU, one wave per node, 4 neighbor slots ----------
__global__ __launch_bounds__(256) void gather_bn_k(
        const ushort_t* __restrict__ Yin,
        const int* __restrict__ csr, const int* __restrict__ rend,
        const int* __restrict__ deg,
        const float* __restrict__ epsp, const float* __restrict__ ba,
        const float* __restrict__ g, const float* __restrict__ be,
        const float* __restrict__ mm, const float* __restrict__ vv,
        ushort_t* __restrict__ H, int nwaves) {
    const int gwid = (blockIdx.x * 256 + threadIdx.x) >> 6;
    const int lane = threadIdx.x & 63;
    const int l15  = lane & 15;
    const int slot = lane >> 4;
    const int c0   = l15 * 8;

    float ep = 1.0f + epsp[0];
    float sc[8], sh[8];
    #pragma unroll
    for (int jj = 0; jj < 8; ++jj) {
        int c = c0 + jj;
        float s = g[c] * rsqrtf(vv[c] + 1e-5f);
        sc[jj] = s;
        sh[jj] = (ba[c] - mm[c]) * s + be[c];
    }

    for (int node = gwid; node < N_NODES; node += nwaves) {
        int end = rend[node];
        int d = deg[node];
        int st = end - d;
        uint4 ow = *reinterpret_cast<const uint4*>(Yin + (size_t)node * 128 + c0);
        int nlim = (d > 64) ? 64 : d;
        int nb = (lane < nlim) ? csr[st + lane] : 0;

        float acc[8] = {0.f, 0.f, 0.f, 0.f, 0.f, 0.f, 0.f, 0.f};
        for (int j0 = 0; j0 < nlim; j0 += 8) {
            int jA = j0 + slot;
            int jB = j0 + 4 + slot;
            int ia = __shfl(nb, jA & 63);
            int ib = __shfl(nb, jB & 63);
            uint4 wa = *reinterpret_cast<const uint4*>(Yin + (size_t)ia * 128 + c0);
            uint4 wb = *reinterpret_cast<const uint4*>(Yin + (size_t)ib * 128 + c0);
            float fa = (jA < nlim) ? 1.f : 0.f;
            float fb = (jB < nlim) ? 1.f : 0.f;
            uint_t ua[4] = {wa.x, wa.y, wa.z, wa.w};
            uint_t ub[4] = {wb.x, wb.y, wb.z, wb.w};
            #pragma unroll
            for (int p = 0; p < 4; ++p) {
                acc[2 * p]     += fa * b2f((ushort_t)(ua[p] & 0xffff));
                acc[2 * p + 1] += fa * b2f((ushort_t)(ua[p] >> 16));
                acc[2 * p]     += fb * b2f((ushort_t)(ub[p] & 0xffff));
                acc[2 * p + 1] += fb * b2f((ushort_t)(ub[p] >> 16));
            }
        }
        for (int j = st + 64; j < end; ++j) {
            if (slot == 0) {
                int idx = csr[j];
                uint4 w = *reinterpret_cast<const uint4*>(Yin + (size_t)idx * 128 + c0);
                uint_t uw[4] = {w.x, w.y, w.z, w.w};
                #pragma unroll
                for (int p = 0; p < 4; ++p) {
                    acc[2 * p]     += b2f((ushort_t)(uw[p] & 0xffff));
                    acc[2 * p + 1] += b2f((ushort_t)(uw[p] >> 16));
                }
            }
        }
        #pragma unroll
        for (int jj = 0; jj < 8; ++jj) {
            acc[jj] += __shfl_xor(acc[jj], 16);
            acc[jj] += __shfl_xor(acc[jj], 32);
        }
        uint_t uo[4] = {ow.x, ow.y, ow.z, ow.w};
        ushort_t rr[8];
        #pragma unroll
        for (int p = 0; p < 4; ++p) {
            float o0 = b2f((ushort_t)(uo[p] & 0xffff));
            float o1 = b2f((ushort_t)(uo[p] >> 16));
            float t0 = sc[2 * p] * (ep * o0 + acc[2 * p]) + sh[2 * p];
            float t1 = sc[2 * p + 1] * (ep * o1 + acc[2 * p + 1]) + sh[2 * p + 1];
            rr[2 * p]     = f2b(fmaxf(t0, 0.f));
            rr[2 * p + 1] = f2b(fmaxf(t1, 0.f));
        }
        if (slot == 0) {
            uint4 packed;
            packed.x = (uint_t)rr[0] | ((uint_t)rr[1] << 16);
            packed.y = (uint_t)rr[2] | ((uint_t)rr[3] << 16);
            packed.z = (uint_t)rr[4] | ((uint_t)rr[5] << 16);
            packed.w = (uint_t)rr[6] | ((uint_t)rr[7] << 16);
            *reinterpret_cast<uint4*>(H + (size_t)node * 128 + c0) = packed;
        }
    }
}

// -------- MLP pair: X=relu(H@Wb+bias); TAIL? pool(X) : Yout = X@Wa2 ----------
template<bool TAIL>
__global__ __launch_bounds__(256) void mlp_k(const ushort_t* __restrict__ Hin,
                                             const ushort_t* __restrict__ Wb,
                                             const float* __restrict__ bias1,
                                             const ushort_t* __restrict__ Wa2,
                                             ushort_t* __restrict__ Yout,
                                             const int* __restrict__ batch,
                                             float* __restrict__ pooled, int M) {
    constexpr int BM = 64;
    constexpr int NJ1 = TAIL ? 2 : 4;       // N1 = 64 or 128
    __shared__ ushort_t Hl[BM * LDP];
    __shared__ ushort_t Xl[BM * LDP];       // also f32 pool staging [64][FLDP]
    float* Fl = (float*)Xl;

    const int tid  = threadIdx.x;
    const int lane = tid & 63;
    const int wid  = tid >> 6;
    const int wrow = wid >> 1;
    const int wcol = wid & 1;
    const int l15  = lane & 15;
    const int kg   = lane >> 4;
    const int row0 = blockIdx.x * BM;

    #pragma unroll
    for (int p = 0; p < 4; ++p) {
        int idx = tid + p * 256;
        int r = idx >> 4, c16 = idx & 15;
        int gr = row0 + r;
        if (gr > M - 1) gr = M - 1;
        *reinterpret_cast<uint4*>(&Hl[r * LDP + c16 * 8]) =
            *reinterpret_cast<const uint4*>(Hin + (size_t)gr * 128 + c16 * 8);
    }
    __syncthreads();

    f32x4 acc1[2][NJ1];
    #pragma unroll
    for (int i = 0; i < 2; ++i)
        #pragma unroll
        for (int j = 0; j < NJ1; ++j)
            acc1[i][j] = f32x4{0.f, 0.f, 0.f, 0.f};
    #pragma unroll
    for (int kk = 0; kk < 4; ++kk) {
        bf16x8 a0 = *reinterpret_cast<const bf16x8*>(&Hl[(wrow * 32 + l15) * LDP + kk * 32 + kg * 8]);
        bf16x8 a1 = *reinterpret_cast<const bf16x8*>(&Hl[(wrow * 32 + 16 + l15) * LDP + kk * 32 + kg * 8]);
        #pragma unroll
        for (int j = 0; j < NJ1; ++j) {
            int col = wcol * (16 * NJ1) + j * 16 + l15;
            bf16x8 b = *reinterpret_cast<const bf16x8*>(Wb + (size_t)col * 128 + kk * 32 + kg * 8);
            acc1[0][j] = __builtin_amdgcn_mfma_f32_16x16x32_bf16(a0, b, acc1[0][j], 0, 0, 0);
            acc1[1][j] = __builtin_amdgcn_mfma_f32_16x16x32_bf16(a1, b, acc1[1][j], 0, 0, 0);
        }
    }

    if constexpr (TAIL) {
        #pragma unroll
        for (int i = 0; i < 2; ++i)
            #pragma unroll
            for (int j = 0; j < NJ1; ++j) {
                int col = wcol * 32 + j * 16 + l15;
                float bi = bias1[col];
                #pragma unroll
                for (int q = 0; q < 4; ++q) {
                    int row = wrow * 32 + i * 16 + kg * 4 + q;
                    Fl[row * FLDP + col] = fmaxf(acc1[i][j][q] + bi, 0.f);
                }
            }
        __syncthreads();
        int col = tid & 63;
        int qq  = tid >> 6;
        float a = 0.f;
        int cur = -1;
        for (int rr = 0; rr < 16; ++rr) {
            int r = qq * 16 + rr;
            int gr = row0 + r;
            if (gr >= M) break;
            int b = batch[gr];
            if (b != cur) {
                if (cur >= 0) atomicAdd(&pooled[cur * 64 + col], a);
                a = 0.f;
                cur = b;
            }
            a += Fl[r * FLDP + col];
        }
        if (cur >= 0) atomicAdd(&pooled[cur * 64 + col], a);
    } else {
        #pragma unroll
        for (int i = 0; i < 2; ++i)
            #pragma unroll
            for (int j = 0; j < NJ1; ++j) {
                int col = wcol * 64 + j * 16 + l15;
                float bi = bias1[col];
                #pragma unroll
                for (int q = 0; q < 4; ++q) {
                    int row = wrow * 32 + i * 16 + kg * 4 + q;
                    Xl[row * LDP + col] = f2b(fmaxf(acc1[i][j][q] + bi, 0.f));
                }
            }
        __syncthreads();

        f32x4 acc2[2][4];
        #pragma unroll
        for (int i = 0; i < 2; ++i)
            #pragma unroll
            for (int j = 0; j < 4; ++j)
                acc2[i][j] = f32x4{0.f, 0.f, 0.f, 0.f};
        #pragma unroll
        for (int kk = 0; kk < 4; ++kk) {
            bf16x8 a0 = *reinterpret_cast<const bf16x8*>(&Xl[(wrow * 32 + l15) * LDP + kk * 32 + kg * 8]);
            bf16x8 a1 = *reinterpret_cast<const bf16x8*>(&Xl[(wrow * 32 + 16 + l15) * LDP + kk * 32 + kg * 8]);
            #pragma unroll
            for (int j = 0; j < 4; ++j) {
                int col = wcol * 64 + j * 16 + l15;
                bf16x8 b = *reinterpret_cast<const bf16x8*>(Wa2 + (size_t)col * 128 + kk * 32 + kg * 8);
                acc2[0][j] = __builtin_amdgcn_mfma_f32_16x16x32_bf16(a0, b, acc2[0][j], 0, 0, 0);
                acc2[1][j] = __builtin_amdgcn_mfma_f32_16x16x32_bf16(a1, b, acc2[1][j], 0, 0, 0);
            }
        }
        #pragma unroll
        for (int i = 0; i < 2; ++i)
            #pragma unroll
            for (int j = 0; j < 4; ++j) {
                int col = wcol * 64 + j * 16 + l15;
                #pragma unroll
                for (int q = 0; q < 4; ++q) {
                    int row = wrow * 32 + i * 16 + kg * 4 + q;
                    Hl[row * LDP + col] = f2b(acc2[i][j][q]);
                }
            }
        __syncthreads();
        #pragma unroll
        for (int p = 0; p < 4; ++p) {
            int idx = tid + p * 256;
            int r = idx >> 4, c16 = idx & 15;
            int gr = row0 + r;
            if (gr < M)
                *reinterpret_cast<uint4*>(Yout + (size_t)gr * 128 + c16 * 8) =
                    *reinterpret_cast<const uint4*>(&Hl[r * LDP + c16 * 8]);
        }
    }
}

// ---------------- classifier ----------------
__global__ __launch_bounds__(256) void classifier_k(const float* __restrict__ pooled,
                                                    const float* __restrict__ wc,
                                                    const float* __restrict__ bc,
                                                    float* __restrict__ out) {
    int t = threadIdx.x;
    int gidx = t >> 1, c = t & 1;
    float s = bc[c];
    #pragma unroll
    for (int k = 0; k < 64; ++k)
        s += pooled[gidx * 64 + k] * wc[k * 2 + c];
    out[gidx * 2 + c] = s;
}

extern "C" void kernel_launch(void* const* d_in, const int* in_sizes, int n_in,
                              void* d_out, int out_size, void* d_ws, size_t ws_size,
                              hipStream_t stream) {
    const float* x     = (const float*)d_in[0];
    const int*   ei    = (const int*)d_in[1];
    const int*   src   = ei;
    const int*   dst   = ei + N_EDGES;
    const int*   batch = (const int*)d_in[2];
    const float* eps1 = (const float*)d_in[3];
    const float* w1a  = (const float*)d_in[4];
    const float* b1a  = (const float*)d_in[5];
    const float* g1   = (const float*)d_in[6];
    const float* be1  = (const float*)d_in[7];
    const float* m1   = (const float*)d_in[8];
    const float* v1   = (const float*)d_in[9];
    const float* w1b  = (const float*)d_in[10];
    const float* b1b  = (const float*)d_in[11];
    const float* eps2 = (const float*)d_in[12];
    const float* w2a  = (const float*)d_in[13];
    const float* b2a  = (const float*)d_in[14];
    const float* g2   = (const float*)d_in[15];
    const float* be2  = (const float*)d_in[16];
    const float* m2   = (const float*)d_in[17];
    const float* v2   = (const float*)d_in[18];
    const float* w2b  = (const float*)d_in[19];
    const float* b2b  = (const float*)d_in[20];
    const float* eps3 = (const float*)d_in[21];
    const float* w3a  = (const float*)d_in[22];
    const float* b3a  = (const float*)d_in[23];
    const float* g3   = (const float*)d_in[24];
    const float* be3  = (const float*)d_in[25];
    const float* m3   = (const float*)d_in[26];
    const float* v3   = (const float*)d_in[27];
    const float* w3b  = (const float*)d_in[28];
    const float* b3b  = (const float*)d_in[29];
    const float* wc   = (const float*)d_in[30];
    const float* bc   = (const float*)d_in[31];
    float* out = (float*)d_out;

    // workspace layout
    ushort_t* Y = (ushort_t*)d_ws;             // [100000,128] bf16
    ushort_t* H = Y + 12800000;                // [100000,128] bf16
    ushort_t* wt1a = H + 12800000;             // 384*128
    ushort_t* wt1b = wt1a + 49152;             // 128*128
    ushort_t* wt2a = wt1b + 16384;
    ushort_t* wt2b = wt2a + 16384;
    ushort_t* wt3a = wt2b + 16384;
    ushort_t* wt3b = wt3a + 16384;             // 64*128
    float* pooled = (float*)(wt3b + 8192);     // [128,64]
    int* ideg = (int*)(pooled + 8192);         // [100000]
    int* irow = ideg + N_NODES;
    int* itmp = irow + N_NODES;
    int* icsr = itmp + N_NODES;                // [800000]
    int* ibsum = icsr + N_EDGES;               // [391]

    const int M = N_NODES;
    const int gGemm = (M + 63) / 64;           // 1563
    const int gG1   = 3125;                    // 12500 waves = 6250 rowgrp x 2
    const int gEdge = (N_EDGES + 255) / 256;   // 3125
    const int gNode = NB_SCAN;                 // 391
    const int gGath = 2048;                    // 8192 waves
    const int nwaves = gGath * 4;

    // ---- all weight transposes (one dispatch) ----
    wt_all_k<<<480, 256, 0, stream>>>(w1a, w1b, w2a, w2b, w3a, w3b,
                                      wt1a, wt1b, wt2a, wt2b, wt3a, wt3b);

    // ---- build CSR ----
    hipMemsetAsync(ideg, 0, N_NODES * sizeof(int), stream);
    hist_k<<<gEdge, 256, 0, stream>>>(dst, ideg);
    scan1_k<<<gNode, 256, 0, stream>>>(ideg, itmp, ibsum);
    scan2_k<<<1, 512, 0, stream>>>(ibsum);
    scan3_k<<<gNode, 256, 0, stream>>>(itmp, ideg, ibsum, irow);
    fill_k<<<gEdge, 256, 0, stream>>>(src, dst, irow, icsr);
    hipMemsetAsync(pooled, 0, (size_t)N_GRAPHS * 64 * sizeof(float), stream);

    // ---- D1: Y1 = x @ w1a ----
    gemm1_k<<<gG1, 256, 0, stream>>>(x, wt1a, Y);

    // ---- layer 1 ----
    gather_bn_k<<<gGath, 256, 0, stream>>>(Y, icsr, irow, ideg, eps1, b1a, g1, be1, m1, v1, H, nwaves);
    mlp_k<false><<<gGemm, 256, 0, stream>>>(H, wt1b, b1b, wt2a, Y, nullptr, nullptr, M);

    // ---- layer 2 ----
    gather_bn_k<<<gGath, 256, 0, stream>>>(Y, icsr, irow, ideg, eps2, b2a, g2, be2, m2, v2, H, nwaves);
    mlp_k<false><<<gGemm, 256, 0, stream>>>(H, wt2b, b2b, wt3a, Y, nullptr, nullptr, M);

    // ---- layer 3 ----
    gather_bn_k<<<gGath, 256, 0, stream>>>(Y, icsr, irow, ideg, eps3, b3a, g3, be3, m3, v3, H, nwaves);
    mlp_k<true><<<gGemm, 256, 0, stream>>>(H, wt3b, b3b, nullptr, nullptr, batch, pooled, M);

    // ---- classifier ----
    classifier_k<<<1, 256, 0, stream>>>(pooled, wc, bc, out);
}

// Round 9
// 428.890 us; speedup vs baseline: 1.0532x; 1.0523x over previous
//
#include <hip/hip_runtime.h>
#include <hip/hip_bf16.h>

// GIN classifier. R8: gemm1 = single-wave 16x128 tile, 24-load register burst
// pinned by sched_barrier(0) (loads cannot sink past it) + launch_bounds(64,2)
// for VGPR budget; A read once. gather_bn pipelined 2-deep across nodes.

#define N_NODES 100000
#define N_EDGES 800000
#define N_GRAPHS 128
#define NB_SCAN 391   // ceil(N_NODES/256)
#define LDP 136       // bf16 LDS row stride (mlp): 2-way bank alias only (free)
#define FLDP 68       // f32 row stride for pool staging

typedef __bf16 bf16x8 __attribute__((ext_vector_type(8)));
typedef float f32x4 __attribute__((ext_vector_type(4)));
typedef unsigned short ushort_t;
typedef unsigned int uint_t;

static __device__ __forceinline__ ushort_t f2b(float f) {
    uint_t u = __builtin_bit_cast(uint_t, f);
    uint_t r = (u + 0x7fffu + ((u >> 16) & 1u)) >> 16;   // RNE
    return (ushort_t)r;
}
static __device__ __forceinline__ float b2f(ushort_t u) {
    return __builtin_bit_cast(float, (uint_t)u << 16);
}

// ------------- all weight transposes in one kernel: Wt[c*K+k] = bf16(W[k*N+c])
__global__ __launch_bounds__(256) void wt_all_k(
        const float* __restrict__ w1a, const float* __restrict__ w1b,
        const float* __restrict__ w2a, const float* __restrict__ w2b,
        const float* __restrict__ w3a, const float* __restrict__ w3b,
        ushort_t* __restrict__ o1a, ushort_t* __restrict__ o1b,
        ushort_t* __restrict__ o2a, ushort_t* __restrict__ o2b,
        ushort_t* __restrict__ o3a, ushort_t* __restrict__ o3b) {
    int t = blockIdx.x * 256 + threadIdx.x;
    const float* W; ushort_t* O; int K, N, i;
    if      (t <  49152) { W = w1a; O = o1a; K = 384; N = 128; i = t; }
    else if (t <  65536) { W = w1b; O = o1b; K = 128; N = 128; i = t - 49152; }
    else if (t <  81920) { W = w2a; O = o2a; K = 128; N = 128; i = t - 65536; }
    else if (t <  98304) { W = w2b; O = o2b; K = 128; N = 128; i = t - 81920; }
    else if (t < 114688) { W = w3a; O = o3a; K = 128; N = 128; i = t - 98304; }
    else if (t < 122880) { W = w3b; O = o3b; K = 128; N = 64;  i = t - 114688; }
    else return;
    int k = i / N, c = i % N;
    O[c * K + k] = f2b(W[i]);
}

// ---------------- D1: C[M,128] = bf16(A fp32 [M,384]) @ Wt ------------------
// One wave per 16-row block, full N=128. 24 independent A loads issued as a
// burst that CANNOT sink past sched_barrier(0) -> 24 outstanding loads/wave,
// A read exactly once. B (96 KB) L2-hot. 6250 single-wave blocks.
__global__ __launch_bounds__(64, 2) void gemm1_k(const float* __restrict__ A,
                                                 const ushort_t* __restrict__ Wt,
                                                 ushort_t* __restrict__ C) {
    constexpr int K = 384;
    constexpr int EP = 136;                  // epilogue LDS row stride (bf16)
    __shared__ __align__(16) ushort_t El[16 * EP];

    const int lane = threadIdx.x;            // 0..63
    const int row0 = blockIdx.x * 16;        // 6250 blocks -> 100000 rows exact
    const int l15  = lane & 15;
    const int kg   = lane >> 4;

    const float*    pA = A  + (size_t)(row0 + l15) * K + kg * 8;
    const ushort_t* pB = Wt + (size_t)l15 * K + kg * 8;

    // ---- burst: all 24 independent A loads issued before ANY consumption ----
    float4 va[24];
    #pragma unroll
    for (int p = 0; p < 24; ++p)
        va[p] = *reinterpret_cast<const float4*>(pA + (p >> 1) * 32 + (p & 1) * 4);
    __builtin_amdgcn_sched_barrier(0);       // loads may not sink below this

    f32x4 acc[8];
    #pragma unroll
    for (int j = 0; j < 8; ++j) acc[j] = f32x4{0.f, 0.f, 0.f, 0.f};

    #pragma unroll
    for (int kk = 0; kk < 12; ++kk) {
        float4 x0 = va[2 * kk], x1 = va[2 * kk + 1];
        bf16x8 af;
        af[0] = (__bf16)x0.x; af[1] = (__bf16)x0.y;
        af[2] = (__bf16)x0.z; af[3] = (__bf16)x0.w;
        af[4] = (__bf16)x1.x; af[5] = (__bf16)x1.y;
        af[6] = (__bf16)x1.z; af[7] = (__bf16)x1.w;
        #pragma unroll
        for (int j = 0; j < 8; ++j) {
            bf16x8 bf = *reinterpret_cast<const bf16x8*>(pB + (size_t)j * 16 * K + kk * 32);
            acc[j] = __builtin_amdgcn_mfma_f32_16x16x32_bf16(af, bf, acc[j], 0, 0, 0);
        }
    }

    // epilogue: stage 16x128 in LDS, full-256B-row coalesced stores
    #pragma unroll
    for (int j = 0; j < 8; ++j)
        #pragma unroll
        for (int q = 0; q < 4; ++q)
            El[(kg * 4 + q) * EP + j * 16 + l15] = f2b(acc[j][q]);
    __syncthreads();                          // single wave: cheap
    #pragma unroll
    for (int p = 0; p < 4; ++p) {
        int r = p * 4 + (lane >> 4);
        *reinterpret_cast<uint4*>(C + (size_t)(row0 + r) * 128 + (lane & 15) * 8) =
            *reinterpret_cast<const uint4*>(&El[r * EP + (lane & 15) * 8]);
    }
}

// ---------------- CSR build ----------------
__global__ __launch_bounds__(256) void hist_k(const int* __restrict__ dst,
                                              int* __restrict__ deg) {
    int e = blockIdx.x * 256 + threadIdx.x;
    if (e < N_EDGES) atomicAdd(&deg[dst[e]], 1);
}

__global__ __launch_bounds__(256) void scan1_k(const int* __restrict__ deg,
                                               int* __restrict__ tmp,
                                               int* __restrict__ bsum) {
    __shared__ int s[256];
    int i = blockIdx.x * 256 + threadIdx.x;
    int t = threadIdx.x;
    s[t] = (i < N_NODES) ? deg[i] : 0;
    __syncthreads();
    for (int off = 1; off < 256; off <<= 1) {
        int v = (t >= off) ? s[t - off] : 0;
        __syncthreads();
        s[t] += v;
        __syncthreads();
    }
    if (i < N_NODES) tmp[i] = s[t];
    if (t == 255) bsum[blockIdx.x] = s[255];
}

__global__ __launch_bounds__(512) void scan2_k(int* __restrict__ bsum) {
    __shared__ int s[512];
    int t = threadIdx.x;
    s[t] = (t < NB_SCAN) ? bsum[t] : 0;
    __syncthreads();
    for (int off = 1; off < 512; off <<= 1) {
        int v = (t >= off) ? s[t - off] : 0;
        __syncthreads();
        s[t] += v;
        __syncthreads();
    }
    if (t < NB_SCAN) bsum[t] = s[t];
}

__global__ __launch_bounds__(256) void scan3_k(const int* __restrict__ tmp,
                                               const int* __restrict__ deg,
                                               const int* __restrict__ bsum,
                                               int* __restrict__ row_start) {
    int i = blockIdx.x * 256 + threadIdx.x;
    if (i >= N_NODES) return;
    int boff = (blockIdx.x > 0) ? bsum[blockIdx.x - 1] : 0;
    row_start[i] = tmp[i] - deg[i] + boff;
}

__global__ __launch_bounds__(256) void fill_k(const int* __restrict__ src,
                                              const int* __restrict__ dst,
                                              int* __restrict__ row_start,
                                              int* __restrict__ csr_src) {
    int e = blockIdx.x * 256 + threadIdx.x;
    if (e >= N_EDGES) return;
    int idx = atomicAdd(&row_start[dst[e]], 1);
    csr_src[idx] = src[e];
}

// ---- gather + BN + ReLU, one wave/node, 4 slots, 2-deep node pipeline ------
__global__ __launch_bounds__(256) void gather_bn_k(
        const ushort_t* __restrict__ Yin,
        const int* __restrict__ csr, const int* __restrict__ rend,
        const int* __restrict__ deg,
        const float* __restrict__ epsp, const float* __restrict__ ba,
        const float* __restrict__ g, const float* __restrict__ be,
        const float* __restrict__ mm, const float* __restrict__ vv,
        ushort_t* __restrict__ H, int nwaves) {
    const int gwid = (blockIdx.x * 256 + threadIdx.x) >> 6;
    const int lane = threadIdx.x & 63;
    const int l15  = lane & 15;
    const int slot = lane >> 4;
    const int c0   = l15 * 8;

    float ep = 1.0f + epsp[0];
    float sc[8], sh[8];
    #pragma unroll
    for (int jj = 0; jj < 8; ++jj) {
        int c = c0 + jj;
        float s = g[c] * rsqrtf(vv[c] + 1e-5f);
        sc[jj] = s;
        sh[jj] = (ba[c] - mm[c]) * s + be[c];
    }

    int node = gwid;
    if (node >= N_NODES) return;
    // prologue: load node 0 meta + indices
    int end = rend[node], d = deg[node];
    int st = end - d;
    int nlim = (d > 64) ? 64 : d;
    int nb = (lane < nlim) ? csr[st + lane] : 0;

    for (; node < N_NODES; node += nwaves) {
        const int nnode = node + nwaves;
        int nend = 0, nd = 0;
        if (nnode < N_NODES) { nend = rend[nnode]; nd = deg[nnode]; }  // prefetch meta

        uint4 ow = *reinterpret_cast<const uint4*>(Yin + (size_t)node * 128 + c0);

        float acc[8] = {0.f, 0.f, 0.f, 0.f, 0.f, 0.f, 0.f, 0.f};
        for (int j0 = 0; j0 < nlim; j0 += 8) {
            int jA = j0 + slot;
            int jB = j0 + 4 + slot;
            int ia = __shfl(nb, jA & 63);
            int ib = __shfl(nb, jB & 63);
            uint4 wa = *reinterpret_cast<const uint4*>(Yin + (size_t)ia * 128 + c0);
            uint4 wb = *reinterpret_cast<const uint4*>(Yin + (size_t)ib * 128 + c0);
            float fa = (jA < nlim) ? 1.f : 0.f;
            float fb = (jB < nlim) ? 1.f : 0.f;
            uint_t ua[4] = {wa.x, wa.y, wa.z, wa.w};
            uint_t ub[4] = {wb.x, wb.y, wb.z, wb.w};
            #pragma unroll
            for (int p = 0; p < 4; ++p) {
                acc[2 * p]     += fa * b2f((ushort_t)(ua[p] & 0xffff));
                acc[2 * p + 1] += fa * b2f((ushort_t)(ua[p] >> 16));
                acc[2 * p]     += fb * b2f((ushort_t)(ub[p] & 0xffff));
                acc[2 * p + 1] += fb * b2f((ushort_t)(ub[p] >> 16));
            }
        }
        for (int j = st + 64; j < end; ++j) {
            if (slot == 0) {
                int idx = csr[j];
                uint4 w = *reinterpret_cast<const uint4*>(Yin + (size_t)idx * 128 + c0);
                uint_t uw[4] = {w.x, w.y, w.z, w.w};
                #pragma unroll
                for (int p = 0; p < 4; ++p) {
                    acc[2 * p]     += b2f((ushort_t)(uw[p] & 0xffff));
                    acc[2 * p + 1] += b2f((ushort_t)(uw[p] >> 16));
                }
            }
        }

        // prefetch next node's indices (overlaps reduce + BN + store)
        int nst = nend - nd;
        int nnlim = (nd > 64) ? 64 : nd;
        int nb2 = 0;
        if (nnode < N_NODES && lane < nnlim) nb2 = csr[nst + lane];

        #pragma unroll
        for (int jj = 0; jj < 8; ++jj) {
            acc[jj] += __shfl_xor(acc[jj], 16);
            acc[jj] += __shfl_xor(acc[jj], 32);
        }
        uint_t uo[4] = {ow.x, ow.y, ow.z, ow.w};
        ushort_t rr[8];
        #pragma unroll
        for (int p = 0; p < 4; ++p) {
            float o0 = b2f((ushort_t)(uo[p] & 0xffff));
            float o1 = b2f((ushort_t)(uo[p] >> 16));
            float t0 = sc[2 * p] * (ep * o0 + acc[2 * p]) + sh[2 * p];
            float t1 = sc[2 * p + 1] * (ep * o1 + acc[2 * p + 1]) + sh[2 * p + 1];
            rr[2 * p]     = f2b(fmaxf(t0, 0.f));
            rr[2 * p + 1] = f2b(fmaxf(t1, 0.f));
        }
        if (slot == 0) {
            uint4 packed;
            packed.x = (uint_t)rr[0] | ((uint_t)rr[1] << 16);
            packed.y = (uint_t)rr[2] | ((uint_t)rr[3] << 16);
            packed.z = (uint_t)rr[4] | ((uint_t)rr[5] << 16);
            packed.w = (uint_t)rr[6] | ((uint_t)rr[7] << 16);
            *reinterpret_cast<uint4*>(H + (size_t)node * 128 + c0) = packed;
        }

        end = nend; d = nd; st = nst; nlim = nnlim; nb = nb2;
    }
}

// -------- MLP pair: X=relu(H@Wb+bias); TAIL? pool(X) : Yout = X@Wa2 ----------
template<bool TAIL>
__global__ __launch_bounds__(256) void mlp_k(const ushort_t* __restrict__ Hin,
                                             const ushort_t* __restrict__ Wb,
                                             const float* __restrict__ bias1,
                                             const ushort_t* __restrict__ Wa2,
                                             ushort_t* __restrict__ Yout,
                                             const int* __restrict__ batch,
                                             float* __restrict__ pooled, int M) {
    constexpr int BM = 64;
    constexpr int NJ1 = TAIL ? 2 : 4;       // N1 = 64 or 128
    __shared__ ushort_t Hl[BM * LDP];
    __shared__ ushort_t Xl[BM * LDP];       // also f32 pool staging [64][FLDP]
    float* Fl = (float*)Xl;

    const int tid  = threadIdx.x;
    const int lane = tid & 63;
    const int wid  = tid >> 6;
    const int wrow = wid >> 1;
    const int wcol = wid & 1;
    const int l15  = lane & 15;
    const int kg   = lane >> 4;
    const int row0 = blockIdx.x * BM;

    #pragma unroll
    for (int p = 0; p < 4; ++p) {
        int idx = tid + p * 256;
        int r = idx >> 4, c16 = idx & 15;
        int gr = row0 + r;
        if (gr > M - 1) gr = M - 1;
        *reinterpret_cast<uint4*>(&Hl[r * LDP + c16 * 8]) =
            *reinterpret_cast<const uint4*>(Hin + (size_t)gr * 128 + c16 * 8);
    }
    __syncthreads();

    f32x4 acc1[2][NJ1];
    #pragma unroll
    for (int i = 0; i < 2; ++i)
        #pragma unroll
        for (int j = 0; j < NJ1; ++j)
            acc1[i][j] = f32x4{0.f, 0.f, 0.f, 0.f};
    #pragma unroll
    for (int kk = 0; kk < 4; ++kk) {
        bf16x8 a0 = *reinterpret_cast<const bf16x8*>(&Hl[(wrow * 32 + l15) * LDP + kk * 32 + kg * 8]);
        bf16x8 a1 = *reinterpret_cast<const bf16x8*>(&Hl[(wrow * 32 + 16 + l15) * LDP + kk * 32 + kg * 8]);
        #pragma unroll
        for (int j = 0; j < NJ1; ++j) {
            int col = wcol * (16 * NJ1) + j * 16 + l15;
            bf16x8 b = *reinterpret_cast<const bf16x8*>(Wb + (size_t)col * 128 + kk * 32 + kg * 8);
            acc1[0][j] = __builtin_amdgcn_mfma_f32_16x16x32_bf16(a0, b, acc1[0][j], 0, 0, 0);
            acc1[1][j] = __builtin_amdgcn_mfma_f32_16x16x32_bf16(a1, b, acc1[1][j], 0, 0, 0);
        }
    }

    if constexpr (TAIL) {
        #pragma unroll
        for (int i = 0; i < 2; ++i)
            #pragma unroll
            for (int j = 0; j < NJ1; ++j) {
                int col = wcol * 32 + j * 16 + l15;
                float bi = bias1[col];
                #pragma unroll
                for (int q = 0; q < 4; ++q) {
                    int row = wrow * 32 + i * 16 + kg * 4 + q;
                    Fl[row * FLDP + col] = fmaxf(acc1[i][j][q] + bi, 0.f);
                }
            }
        __syncthreads();
        int col = tid & 63;
        int qq  = tid >> 6;
        float a = 0.f;
        int cur = -1;
        for (int rr = 0; rr < 16; ++rr) {
            int r = qq * 16 + rr;
            int gr = row0 + r;
            if (gr >= M) break;
            int b = batch[gr];
            if (b != cur) {
                if (cur >= 0) atomicAdd(&pooled[cur * 64 + col], a);
                a = 0.f;
                cur = b;
            }
            a += Fl[r * FLDP + col];
        }
        if (cur >= 0) atomicAdd(&pooled[cur * 64 + col], a);
    } else {
        #pragma unroll
        for (int i = 0; i < 2; ++i)
            #pragma unroll
            for (int j = 0; j < NJ1; ++j) {
                int col = wcol * 64 + j * 16 + l15;
                float bi = bias1[col];
                #pragma unroll
                for (int q = 0; q < 4; ++q) {
                    int row = wrow * 32 + i * 16 + kg * 4 + q;
                    Xl[row * LDP + col] = f2b(fmaxf(acc1[i][j][q] + bi, 0.f));
                }
            }
        __syncthreads();

        f32x4 acc2[2][4];
        #pragma unroll
        for (int i = 0; i < 2; ++i)
            #pragma unroll
            for (int j = 0; j < 4; ++j)
                acc2[i][j] = f32x4{0.f, 0.f, 0.f, 0.f};
        #pragma unroll
        for (int kk = 0; kk < 4; ++kk) {
            bf16x8 a0 = *reinterpret_cast<const bf16x8*>(&Xl[(wrow * 32 + l15) * LDP + kk * 32 + kg * 8]);
            bf16x8 a1 = *reinterpret_cast<const bf16x8*>(&Xl[(wrow * 32 + 16 + l15) * LDP + kk * 32 + kg * 8]);
            #pragma unroll
            for (int j = 0; j < 4; ++j) {
                int col = wcol * 64 + j * 16 + l15;
                bf16x8 b = *reinterpret_cast<const bf16x8*>(Wa2 + (size_t)col * 128 + kk * 32 + kg * 8);
                acc2[0][j] = __builtin_amdgcn_mfma_f32_16x16x32_bf16(a0, b, acc2[0][j], 0, 0, 0);
                acc2[1][j] = __builtin_amdgcn_mfma_f32_16x16x32_bf16(a1, b, acc2[1][j], 0, 0, 0);
            }
        }
        #pragma unroll
        for (int i = 0; i < 2; ++i)
            #pragma unroll
            for (int j = 0; j < 4; ++j) {
                int col = wcol * 64 + j * 16 + l15;
                #pragma unroll
                for (int q = 0; q < 4; ++q) {
                    int row = wrow * 32 + i * 16 + kg * 4 + q;
                    Hl[row * LDP + col] = f2b(acc2[i][j][q]);
                }
            }
        __syncthreads();
        #pragma unroll
        for (int p = 0; p < 4; ++p) {
            int idx = tid + p * 256;
            int r = idx >> 4, c16 = idx & 15;
            int gr = row0 + r;
            if (gr < M)
                *reinterpret_cast<uint4*>(Yout + (size_t)gr * 128 + c16 * 8) =
                    *reinterpret_cast<const uint4*>(&Hl[r * LDP + c16 * 8]);
        }
    }
}

// ---------------- classifier ----------------
__global__ __launch_bounds__(256) void classifier_k(const float* __restrict__ pooled,
                                                    const float* __restrict__ wc,
                                                    const float* __restrict__ bc,
                                                    float* __restrict__ out) {
    int t = threadIdx.x;
    int gidx = t >> 1, c = t & 1;
    float s = bc[c];
    #pragma unroll
    for (int k = 0; k < 64; ++k)
        s += pooled[gidx * 64 + k] * wc[k * 2 + c];
    out[gidx * 2 + c] = s;
}

extern "C" void kernel_launch(void* const* d_in, const int* in_sizes, int n_in,
                              void* d_out, int out_size, void* d_ws, size_t ws_size,
                              hipStream_t stream) {
    const float* x     = (const float*)d_in[0];
    const int*   ei    = (const int*)d_in[1];
    const int*   src   = ei;
    const int*   dst   = ei + N_EDGES;
    const int*   batch = (const int*)d_in[2];
    const float* eps1 = (const float*)d_in[3];
    const float* w1a  = (const float*)d_in[4];
    const float* b1a  = (const float*)d_in[5];
    const float* g1   = (const float*)d_in[6];
    const float* be1  = (const float*)d_in[7];
    const float* m1   = (const float*)d_in[8];
    const float* v1   = (const float*)d_in[9];
    const float* w1b  = (const float*)d_in[10];
    const float* b1b  = (const float*)d_in[11];
    const float* eps2 = (const float*)d_in[12];
    const float* w2a  = (const float*)d_in[13];
    const float* b2a  = (const float*)d_in[14];
    const float* g2   = (const float*)d_in[15];
    const float* be2  = (const float*)d_in[16];
    const float* m2   = (const float*)d_in[17];
    const float* v2   = (const float*)d_in[18];
    const float* w2b  = (const float*)d_in[19];
    const float* b2b  = (const float*)d_in[20];
    const float* eps3 = (const float*)d_in[21];
    const float* w3a  = (const float*)d_in[22];
    const float* b3a  = (const float*)d_in[23];
    const float* g3   = (const float*)d_in[24];
    const float* be3  = (const float*)d_in[25];
    const float* m3   = (const float*)d_in[26];
    const float* v3   = (const float*)d_in[27];
    const float* w3b  = (const float*)d_in[28];
    const float* b3b  = (const float*)d_in[29];
    const float* wc   = (const float*)d_in[30];
    const float* bc   = (const float*)d_in[31];
    float* out = (float*)d_out;

    // workspace layout
    ushort_t* Y = (ushort_t*)d_ws;             // [100000,128] bf16
    ushort_t* H = Y + 12800000;                // [100000,128] bf16
    ushort_t* wt1a = H + 12800000;             // 384*128
    ushort_t* wt1b = wt1a + 49152;             // 128*128
    ushort_t* wt2a = wt1b + 16384;
    ushort_t* wt2b = wt2a + 16384;
    ushort_t* wt3a = wt2b + 16384;
    ushort_t* wt3b = wt3a + 16384;             // 64*128
    float* pooled = (float*)(wt3b + 8192);     // [128,64]
    int* ideg = (int*)(pooled + 8192);         // [100000]
    int* irow = ideg + N_NODES;
    int* itmp = irow + N_NODES;
    int* icsr = itmp + N_NODES;                // [800000]
    int* ibsum = icsr + N_EDGES;               // [391]

    const int M = N_NODES;
    const int gGemm = (M + 63) / 64;           // 1563
    const int gG1   = 6250;                    // one 16-row wave per block
    const int gEdge = (N_EDGES + 255) / 256;   // 3125
    const int gNode = NB_SCAN;                 // 391
    const int gGath = 2048;                    // 8192 waves
    const int nwaves = gGath * 4;

    // ---- all weight transposes (one dispatch) ----
    wt_all_k<<<480, 256, 0, stream>>>(w1a, w1b, w2a, w2b, w3a, w3b,
                                      wt1a, wt1b, wt2a, wt2b, wt3a, wt3b);

    // ---- build CSR ----
    hipMemsetAsync(ideg, 0, N_NODES * sizeof(int), stream);
    hist_k<<<gEdge, 256, 0, stream>>>(dst, ideg);
    scan1_k<<<gNode, 256, 0, stream>>>(ideg, itmp, ibsum);
    scan2_k<<<1, 512, 0, stream>>>(ibsum);
    scan3_k<<<gNode, 256, 0, stream>>>(itmp, ideg, ibsum, irow);
    fill_k<<<gEdge, 256, 0, stream>>>(src, dst, irow, icsr);
    hipMemsetAsync(pooled, 0, (size_t)N_GRAPHS * 64 * sizeof(float), stream);

    // ---- D1: Y1 = x @ w1a ----
    gemm1_k<<<gG1, 64, 0, stream>>>(x, wt1a, Y);

    // ---- layer 1 ----
    gather_bn_k<<<gGath, 256, 0, stream>>>(Y, icsr, irow, ideg, eps1, b1a, g1, be1, m1, v1, H, nwaves);
    mlp_k<false><<<gGemm, 256, 0, stream>>>(H, wt1b, b1b, wt2a, Y, nullptr, nullptr, M);

    // ---- layer 2 ----
    gather_bn_k<<<gGath, 256, 0, stream>>>(Y, icsr, irow, ideg, eps2, b2a, g2, be2, m2, v2, H, nwaves);
    mlp_k<false><<<gGemm, 256, 0, stream>>>(H, wt2b, b2b, wt3a, Y, nullptr, nullptr, M);

    // ---- layer 3 ----
    gather_bn_k<<<gGath, 256, 0, stream>>>(Y, icsr, irow, ideg, eps3, b3a, g3, be3, m3, v3, H, nwaves);
    mlp_k<true><<<gGemm, 256, 0, stream>>>(H, wt3b, b3b, nullptr, nullptr, batch, pooled, M);

    // ---- classifier ----
    classifier_k<<<1, 256, 0, stream>>>(pooled, wc, bc, out);
}